// Round 1
// baseline (1893.040 us; speedup 1.0000x reference)
//
#include <hip/hip_runtime.h>
#include <math.h>

#define HH 128
#define WW 128
#define CCH 256          // C
#define C2 512           // 2C
#define HID 64
#define NPIX (HH*WW)     // 16384
#define BB 8

// workspace layout (floats)
#define OFF4_OFF   0          // [B][H][W][4] = 524288
#define POOLED_OFF 524288     // [B][512]
#define MOD_OFF    528384     // [B][256]
#define W4_OFF     530432     // [4][64]
#define B4_OFF     530688     // [4]

// ---------------- K0: fold p2 into 4 output channels -----------------
__global__ void k_prep(const float* __restrict__ p2_w, const float* __restrict__ p2_b,
                       float* __restrict__ w4, float* __restrict__ b4) {
    int h = threadIdx.x;  // 64 threads
#pragma unroll
    for (int j = 0; j < 4; j++) {
        int r0 = (j >> 1) * 8 + (j & 1);
        w4[j * 64 + h] = 0.25f * (p2_w[(r0 + 0) * 64 + h] + p2_w[(r0 + 2) * 64 + h] +
                                  p2_w[(r0 + 4) * 64 + h] + p2_w[(r0 + 6) * 64 + h]);
        if (h == 0)
            b4[j] = 0.25f * (p2_b[r0] + p2_b[r0 + 2] + p2_b[r0 + 4] + p2_b[r0 + 6]);
    }
}

// ---------------- K1: global average pool over H*W --------------------
__global__ __launch_bounds__(256) void k_pool(const float* __restrict__ rgb,
                                              const float* __restrict__ tir,
                                              float* __restrict__ pooled) {
    int bc = blockIdx.x;            // 0..4095  (b*512 + c)
    int b = bc >> 9;
    int c = bc & 511;
    const float* plane = (c < CCH) ? rgb + (size_t)(b * CCH + c) * NPIX
                                   : tir + (size_t)(b * CCH + (c - CCH)) * NPIX;
    float s = 0.f;
    for (int i = threadIdx.x; i < NPIX; i += 256) s += plane[i];
#pragma unroll
    for (int off = 32; off >= 1; off >>= 1) s += __shfl_down(s, off, 64);
    __shared__ float red[4];
    int wave = threadIdx.x >> 6;
    if ((threadIdx.x & 63) == 0) red[wave] = s;
    __syncthreads();
    if (threadIdx.x == 0) {
        float t = red[0] + red[1] + red[2] + red[3];
        pooled[bc] = t * (1.0f / (float)NPIX);
    }
}

// ---------------- K2: modulation MLP ----------------------------------
__global__ void k_mod(const float* __restrict__ pooled,
                      const float* __restrict__ m1_w, const float* __restrict__ m1_b,
                      const float* __restrict__ m2_w, const float* __restrict__ m2_b,
                      float* __restrict__ mod) {
    __shared__ float pl[C2];
    __shared__ float m[HID];
    int b = blockIdx.x;
    int t = threadIdx.x;  // 64 threads
    for (int i = t; i < C2; i += 64) pl[i] = pooled[b * C2 + i];
    __syncthreads();
    float acc = m1_b[t];
    for (int c = 0; c < C2; c++) acc = fmaf(pl[c], m1_w[t * C2 + c], acc);
    m[t] = fmaxf(acc, 0.f);
    __syncthreads();
    for (int c = t; c < CCH; c += 64) {
        float a = m2_b[c];
#pragma unroll
        for (int h = 0; h < HID; h++) a = fmaf(m[h], m2_w[c * HID + h], a);
        mod[b * CCH + c] = 1.f / (1.f + expf(-a));
    }
}

// ---------------- K3: dwconv3x3 + 512->64 dense + ReLU + 64->4 --------
__global__ __launch_bounds__(256) void k_offsets(
        const float* __restrict__ rgb, const float* __restrict__ tir,
        const float* __restrict__ dw_w, const float* __restrict__ dw_b,
        const float* __restrict__ p1_w, const float* __restrict__ p1_b,
        const float* __restrict__ w4, const float* __restrict__ b4,
        float* __restrict__ off4) {
    __shared__ float lds_p1[64 * 65];   // [cc][h], stride 65 to kill bank conflicts
    int blk = blockIdx.x;               // 0..511
    int b = blk >> 6;
    int y = ((blk & 63) << 1) + (threadIdx.x >> 7);
    int x = threadIdx.x & 127;

    float hidden[HID];
#pragma unroll
    for (int h = 0; h < HID; h++) hidden[h] = 0.f;

    for (int chunk = 0; chunk < 8; chunk++) {
        int c0 = chunk * 64;
        __syncthreads();
#pragma unroll
        for (int i = 0; i < 16; i++) {
            int idx = threadIdx.x + i * 256;       // 0..4095
            int hh = idx >> 6;
            int cc2 = idx & 63;
            lds_p1[cc2 * 65 + hh] = p1_w[hh * C2 + c0 + cc2];
        }
        __syncthreads();

        for (int cc = 0; cc < 64; cc++) {
            int c = c0 + cc;
            const float* plane = (c < CCH) ? rgb + (size_t)(b * CCH + c) * NPIX
                                           : tir + (size_t)(b * CCH + c - CCH) * NPIX;
            const float* wk = dw_w + c * 9;
            float dwacc = dw_b[c];
#pragma unroll
            for (int ky = 0; ky < 3; ky++) {
                int yy = y - 1 + ky;
                bool yok = (yy >= 0) && (yy < HH);
                int yc = yok ? yy : y;              // safe in-bounds address
#pragma unroll
                for (int kx = 0; kx < 3; kx++) {
                    int xx = x - 1 + kx;
                    bool xok = (xx >= 0) && (xx < WW);
                    int xc = xok ? xx : x;
                    float v = plane[yc * WW + xc];
                    v = (yok && xok) ? v : 0.f;     // zero padding (SAME)
                    dwacc = fmaf(v, wk[ky * 3 + kx], dwacc);
                }
            }
            const float* wp = &lds_p1[cc * 65];
#pragma unroll
            for (int h = 0; h < HID; h++) hidden[h] = fmaf(dwacc, wp[h], hidden[h]);
        }
    }

    float off[4];
#pragma unroll
    for (int j = 0; j < 4; j++) off[j] = b4[j];
#pragma unroll
    for (int h = 0; h < HID; h++) {
        float hv = fmaxf(hidden[h] + p1_b[h], 0.f);
#pragma unroll
        for (int j = 0; j < 4; j++) off[j] = fmaf(hv, w4[j * 64 + h], off[j]);
    }
    float4 o4 = make_float4(off[0], off[1], off[2], off[3]);
    *(float4*)&off4[((size_t)b * NPIX + y * WW + x) * 4] = o4;
}

// ---------------- K4: bilinear sample (border, align_corners) + outputs
__global__ __launch_bounds__(256) void k_sample(
        const float* __restrict__ rgb, const float* __restrict__ tir,
        const float* __restrict__ off4, const float* __restrict__ mod,
        float* __restrict__ out) {
    int p = blockIdx.x * 256 + threadIdx.x;   // 0..131071
    int b = p >> 14;
    int rem = p & 16383;
    int y = rem >> 7;
    int x = rem & 127;

    float4 o = *(const float4*)&off4[(size_t)p * 4];
    const float S = 0.1f * 63.5f;   // 0.1 * 0.5*(W-1)
    float ixr = fminf(fmaxf((float)x + o.x * S, 0.f), 127.f);
    float iyr = fminf(fmaxf((float)y + o.y * S, 0.f), 127.f);
    float ixt = fminf(fmaxf((float)x + o.z * S, 0.f), 127.f);
    float iyt = fminf(fmaxf((float)y + o.w * S, 0.f), 127.f);

    float x0r = floorf(ixr), y0r = floorf(iyr);
    float x0t = floorf(ixt), y0t = floorf(iyt);
    int x0ri = (int)x0r, y0ri = (int)y0r, x0ti = (int)x0t, y0ti = (int)y0t;
    int x1ri = min(x0ri + 1, 127), y1ri = min(y0ri + 1, 127);
    int x1ti = min(x0ti + 1, 127), y1ti = min(y0ti + 1, 127);
    float wxr = ixr - x0r, wyr = iyr - y0r;
    float wxt = ixt - x0t, wyt = iyt - y0t;

    int o00r = y0ri * WW + x0ri, o01r = y0ri * WW + x1ri;
    int o10r = y1ri * WW + x0ri, o11r = y1ri * WW + x1ri;
    int o00t = y0ti * WW + x0ti, o01t = y0ti * WW + x1ti;
    int o10t = y1ti * WW + x0ti, o11t = y1ti * WW + x1ti;

    const float* rp = rgb + (size_t)b * CCH * NPIX;
    const float* tp = tir + (size_t)b * CCH * NPIX;
    float* out_r = out + (size_t)b * CCH * NPIX;
    float* out_t = out + (size_t)BB * CCH * NPIX + (size_t)b * CCH * NPIX;
    const float* modb = mod + b * CCH;
    int pix = y * WW + x;

    float qacc = 0.f;
    for (int c = 0; c < CCH; c++) {
        const float* rpc = rp + (size_t)c * NPIX;
        float v00 = rpc[o00r], v01 = rpc[o01r], v10 = rpc[o10r], v11 = rpc[o11r];
        float topr = v00 + (v01 - v00) * wxr;
        float botr = v10 + (v11 - v10) * wxr;
        float sr = topr + (botr - topr) * wyr;

        const float* tpc = tp + (size_t)c * NPIX;
        float u00 = tpc[o00t], u01 = tpc[o01t], u10 = tpc[o10t], u11 = tpc[o11t];
        float topt = u00 + (u01 - u00) * wxt;
        float bott = u10 + (u11 - u10) * wxt;
        float st = topt + (bott - topt) * wyt;

        float mo = modb[c];
        float ra = sr * mo;
        float ta = st * mo;
        out_r[(size_t)c * NPIX + pix] = ra;
        out_t[(size_t)c * NPIX + pix] = ta;
        qacc += fabsf(ra - ta);
    }
    float q = 1.f - qacc * (1.f / (float)CCH);
    out[(size_t)2 * BB * CCH * NPIX + (size_t)b * NPIX + pix] = 1.f / (1.f + expf(-q));
}

extern "C" void kernel_launch(void* const* d_in, const int* in_sizes, int n_in,
                              void* d_out, int out_size, void* d_ws, size_t ws_size,
                              hipStream_t stream) {
    const float* rgb  = (const float*)d_in[0];
    const float* tir  = (const float*)d_in[1];
    const float* dw_w = (const float*)d_in[2];
    const float* dw_b = (const float*)d_in[3];
    const float* p1_w = (const float*)d_in[4];
    const float* p1_b = (const float*)d_in[5];
    const float* p2_w = (const float*)d_in[6];
    const float* p2_b = (const float*)d_in[7];
    const float* m1_w = (const float*)d_in[8];
    const float* m1_b = (const float*)d_in[9];
    const float* m2_w = (const float*)d_in[10];
    const float* m2_b = (const float*)d_in[11];
    float* out = (float*)d_out;
    float* ws  = (float*)d_ws;

    float* off4   = ws + OFF4_OFF;
    float* pooled = ws + POOLED_OFF;
    float* modw   = ws + MOD_OFF;
    float* w4     = ws + W4_OFF;
    float* b4     = ws + B4_OFF;

    hipLaunchKernelGGL(k_prep, dim3(1), dim3(64), 0, stream, p2_w, p2_b, w4, b4);
    hipLaunchKernelGGL(k_pool, dim3(BB * C2), dim3(256), 0, stream, rgb, tir, pooled);
    hipLaunchKernelGGL(k_mod, dim3(BB), dim3(64), 0, stream,
                       pooled, m1_w, m1_b, m2_w, m2_b, modw);
    hipLaunchKernelGGL(k_offsets, dim3(BB * (HH / 2)), dim3(256), 0, stream,
                       rgb, tir, dw_w, dw_b, p1_w, p1_b, w4, b4, off4);
    hipLaunchKernelGGL(k_sample, dim3(BB * NPIX / 256), dim3(256), 0, stream,
                       rgb, tir, off4, modw, out);
}

// Round 2
// 809.444 us; speedup vs baseline: 2.3387x; 2.3387x over previous
//
#include <hip/hip_runtime.h>
#include <math.h>

#define HH 128
#define WW 128
#define CCH 256          // C
#define C2 512           // 2C
#define HID 64
#define NPIX (HH*WW)     // 16384
#define BB 8

// workspace layout (floats)
#define OFF4_OFF   0          // [B][H][W][4] = 524288
#define POOLED_OFF 524288     // [B][512]
#define MOD_OFF    528384     // [B][256]
#define W4_OFF     530432     // [4][64]
#define B4_OFF     530688     // [4]
#define P1B_OFF    530692     // p1_w as bf16 [64][512] = 32768 shorts = 16384 floats

typedef float f32x4 __attribute__((ext_vector_type(4)));
typedef short s16x8 __attribute__((ext_vector_type(8)));

__device__ __forceinline__ unsigned bf16rne(float f) {
    unsigned u = __float_as_uint(f);
    return (u + 0x7FFFu + ((u >> 16) & 1u)) >> 16;
}

// ---------------- K0: fold p2 into 4 output channels + convert p1 to bf16
__global__ void k_prep(const float* __restrict__ p2_w, const float* __restrict__ p2_b,
                       float* __restrict__ w4, float* __restrict__ b4) {
    int h = threadIdx.x;  // 64 threads
#pragma unroll
    for (int j = 0; j < 4; j++) {
        int r0 = (j >> 1) * 8 + (j & 1);
        w4[j * 64 + h] = 0.25f * (p2_w[(r0 + 0) * 64 + h] + p2_w[(r0 + 2) * 64 + h] +
                                  p2_w[(r0 + 4) * 64 + h] + p2_w[(r0 + 6) * 64 + h]);
        if (h == 0)
            b4[j] = 0.25f * (p2_b[r0] + p2_b[r0 + 2] + p2_b[r0 + 4] + p2_b[r0 + 6]);
    }
}

__global__ void k_prep_p1(const float* __restrict__ p1_w, unsigned short* __restrict__ p1bf) {
    int i = blockIdx.x * 256 + threadIdx.x;   // 0..32767, layout [h][c] row-major (as p1_w)
    p1bf[i] = (unsigned short)bf16rne(p1_w[i]);
}

// ---------------- K1: global average pool over H*W --------------------
__global__ __launch_bounds__(256) void k_pool(const float* __restrict__ rgb,
                                              const float* __restrict__ tir,
                                              float* __restrict__ pooled) {
    int bc = blockIdx.x;            // 0..4095  (b*512 + c)
    int b = bc >> 9;
    int c = bc & 511;
    const float* plane = (c < CCH) ? rgb + (size_t)(b * CCH + c) * NPIX
                                   : tir + (size_t)(b * CCH + (c - CCH)) * NPIX;
    const float4* p4 = (const float4*)plane;
    float s = 0.f;
#pragma unroll 4
    for (int i = threadIdx.x; i < NPIX / 4; i += 256) {
        float4 v = p4[i];
        s += (v.x + v.y) + (v.z + v.w);
    }
#pragma unroll
    for (int off = 32; off >= 1; off >>= 1) s += __shfl_down(s, off, 64);
    __shared__ float red[4];
    int wave = threadIdx.x >> 6;
    if ((threadIdx.x & 63) == 0) red[wave] = s;
    __syncthreads();
    if (threadIdx.x == 0) {
        float t = red[0] + red[1] + red[2] + red[3];
        pooled[bc] = t * (1.0f / (float)NPIX);
    }
}

// ---------------- K2: modulation MLP ----------------------------------
__global__ void k_mod(const float* __restrict__ pooled,
                      const float* __restrict__ m1_w, const float* __restrict__ m1_b,
                      const float* __restrict__ m2_w, const float* __restrict__ m2_b,
                      float* __restrict__ mod) {
    __shared__ float pl[C2];
    __shared__ float m[HID];
    int b = blockIdx.x;
    int t = threadIdx.x;  // 64 threads
    for (int i = t; i < C2; i += 64) pl[i] = pooled[b * C2 + i];
    __syncthreads();
    float acc = m1_b[t];
    for (int c = 0; c < C2; c++) acc = fmaf(pl[c], m1_w[t * C2 + c], acc);
    m[t] = fmaxf(acc, 0.f);
    __syncthreads();
    for (int c = t; c < CCH; c += 64) {
        float a = m2_b[c];
#pragma unroll
        for (int h = 0; h < HID; h++) a = fmaf(m[h], m2_w[c * HID + h], a);
        mod[b * CCH + c] = 1.f / (1.f + expf(-a));
    }
}

// ---------------- K3: dwconv3x3 -> bf16 -> MFMA GEMM (512->64) -> fold
// Block: 256 threads (4 waves), tile = 2 rows x 128 cols = 256 px.
// hidden[256 px][64 h] = DW[256 px][512 ch] x p1^T[512 ch][64 h] via
// mfma_f32_16x16x32_bf16; K-loop = 16 steps of 32 channels.
// Grid: 512 blocks; b = blockIdx&7 so each XCD owns one image (halo L2 reuse).
__global__ __launch_bounds__(256, 2) void k_offsets(
        const float* __restrict__ rgb, const float* __restrict__ tir,
        const float* __restrict__ dw_w, const float* __restrict__ dw_b,
        const float* __restrict__ p1_b, const unsigned short* __restrict__ p1bf,
        const float* __restrict__ w4, const float* __restrict__ b4,
        float* __restrict__ off4) {
    // A tile: [256 px][40] bf16 (32 used + pad to keep b128 16B-aligned,
    // stride 80B -> read bank = (m*20+q*4)%32, worst 2-way = free)
    __shared__ __align__(16) unsigned short A_lds[256 * 40];

    const int tid = threadIdx.x;
    const int b   = blockIdx.x & 7;
    const int yp  = blockIdx.x >> 3;
    const int y0  = yp * 2;
    const int m   = tid;              // tile-local pixel index (A row)
    const int py  = y0 + (m >> 7);
    const int px  = m & 127;

    // 3x3 tap offsets + validity (zero padding SAME), clamped safe address
    int  toff[9];
    bool tval[9];
#pragma unroll
    for (int ky = 0; ky < 3; ky++) {
        int yy = py - 1 + ky;
        bool yok = (yy >= 0) && (yy < HH);
        int yc = yok ? yy : py;
#pragma unroll
        for (int kx = 0; kx < 3; kx++) {
            int xx = px - 1 + kx;
            bool xok = (xx >= 0) && (xx < WW);
            int xc = xok ? xx : px;
            toff[ky * 3 + kx] = yc * WW + xc;
            tval[ky * 3 + kx] = yok && xok;
        }
    }

    const int lane = tid & 63;
    const int wv   = tid >> 6;
    const int q    = lane >> 4;
    const int n    = lane & 15;

    f32x4 acc[4][4];   // [mt][nt]
#pragma unroll
    for (int mt = 0; mt < 4; mt++)
#pragma unroll
        for (int nt = 0; nt < 4; nt++) acc[mt][nt] = (f32x4){0.f, 0.f, 0.f, 0.f};

    for (int ks = 0; ks < 16; ks++) {
        const int k0 = ks * 32;
        const float* plane0 = (k0 < CCH)
            ? rgb + (size_t)(b * CCH + k0) * NPIX
            : tir + (size_t)(b * CCH + (k0 - CCH)) * NPIX;
        const float* wdw = dw_w + k0 * 9;
        const float* bdw = dw_b + k0;

        // ---- phase 1: 32 dwconv values for my pixel -> bf16 -> LDS ----
#pragma unroll
        for (int g = 0; g < 4; g++) {
            unsigned pk[4];
#pragma unroll
            for (int jp = 0; jp < 4; jp++) {
                float d[2];
#pragma unroll
                for (int jj = 0; jj < 2; jj++) {
                    int cl = g * 8 + jp * 2 + jj;
                    const float* pl = plane0 + (size_t)cl * NPIX;
                    const float* wk = wdw + cl * 9;
                    float a = bdw[cl];
#pragma unroll
                    for (int t = 0; t < 9; t++) {
                        float v = pl[toff[t]];
                        v = tval[t] ? v : 0.f;
                        a = fmaf(v, wk[t], a);
                    }
                    d[jj] = a;
                }
                pk[jp] = bf16rne(d[0]) | (bf16rne(d[1]) << 16);
            }
            *(int4*)&A_lds[m * 40 + g * 8] = make_int4(pk[0], pk[1], pk[2], pk[3]);
        }
        __syncthreads();

        // ---- phase 2: MFMA ----
        s16x8 af[4], bfr[4];
#pragma unroll
        for (int mt = 0; mt < 4; mt++)
            af[mt] = *(const s16x8*)&A_lds[(wv * 64 + mt * 16 + n) * 40 + q * 8];
#pragma unroll
        for (int nt = 0; nt < 4; nt++)
            bfr[nt] = *(const s16x8*)(p1bf + (nt * 16 + n) * 512 + k0 + q * 8);
#pragma unroll
        for (int mt = 0; mt < 4; mt++)
#pragma unroll
            for (int nt = 0; nt < 4; nt++)
                acc[mt][nt] = __builtin_amdgcn_mfma_f32_16x16x32_bf16(
                    af[mt], bfr[nt], acc[mt][nt], 0, 0, 0);
        __syncthreads();
    }

    // ---- epilogue: bias + ReLU + fold to 4 offsets, reduce over h ----
    float w4v[4][4], b1v[4];
#pragma unroll
    for (int nt = 0; nt < 4; nt++) {
        int h = nt * 16 + n;
        b1v[nt] = p1_b[h];
#pragma unroll
        for (int j = 0; j < 4; j++) w4v[j][nt] = w4[j * 64 + h];
    }
    float bb0 = b4[0], bb1 = b4[1], bb2 = b4[2], bb3 = b4[3];

#pragma unroll
    for (int mt = 0; mt < 4; mt++) {
#pragma unroll
        for (int r = 0; r < 4; r++) {
            float p0 = 0.f, p1 = 0.f, p2 = 0.f, p3 = 0.f;
#pragma unroll
            for (int nt = 0; nt < 4; nt++) {
                float v = fmaxf(acc[mt][nt][r] + b1v[nt], 0.f);
                p0 = fmaf(v, w4v[0][nt], p0);
                p1 = fmaf(v, w4v[1][nt], p1);
                p2 = fmaf(v, w4v[2][nt], p2);
                p3 = fmaf(v, w4v[3][nt], p3);
            }
#pragma unroll
            for (int s = 1; s < 16; s <<= 1) {   // reduce over n (h) lanes
                p0 += __shfl_xor(p0, s, 64);
                p1 += __shfl_xor(p1, s, 64);
                p2 += __shfl_xor(p2, s, 64);
                p3 += __shfl_xor(p3, s, 64);
            }
            if (n == 0) {
                int mm = wv * 64 + mt * 16 + q * 4 + r;
                int pyy = y0 + (mm >> 7), pxx = mm & 127;
                float4 o = make_float4(p0 + bb0, p1 + bb1, p2 + bb2, p3 + bb3);
                *(float4*)&off4[((size_t)b * NPIX + pyy * WW + pxx) * 4] = o;
            }
        }
    }
}

// ---------------- K4: bilinear sample (border, align_corners) + outputs
__global__ __launch_bounds__(256) void k_sample(
        const float* __restrict__ rgb, const float* __restrict__ tir,
        const float* __restrict__ off4, const float* __restrict__ mod,
        float* __restrict__ out) {
    int bid = blockIdx.x;
    int swz = (bid & 7) * 64 + (bid >> 3);    // each XCD owns one image
    int p = swz * 256 + threadIdx.x;          // 0..131071
    int b = p >> 14;
    int rem = p & 16383;
    int y = rem >> 7;
    int x = rem & 127;

    float4 o = *(const float4*)&off4[(size_t)p * 4];
    const float S = 0.1f * 63.5f;
    float ixr = fminf(fmaxf((float)x + o.x * S, 0.f), 127.f);
    float iyr = fminf(fmaxf((float)y + o.y * S, 0.f), 127.f);
    float ixt = fminf(fmaxf((float)x + o.z * S, 0.f), 127.f);
    float iyt = fminf(fmaxf((float)y + o.w * S, 0.f), 127.f);

    float x0r = floorf(ixr), y0r = floorf(iyr);
    float x0t = floorf(ixt), y0t = floorf(iyt);
    int x0ri = (int)x0r, y0ri = (int)y0r, x0ti = (int)x0t, y0ti = (int)y0t;
    int x1ri = min(x0ri + 1, 127), y1ri = min(y0ri + 1, 127);
    int x1ti = min(x0ti + 1, 127), y1ti = min(y0ti + 1, 127);
    float wxr = ixr - x0r, wyr = iyr - y0r;
    float wxt = ixt - x0t, wyt = iyt - y0t;

    int o00r = y0ri * WW + x0ri, o01r = y0ri * WW + x1ri;
    int o10r = y1ri * WW + x0ri, o11r = y1ri * WW + x1ri;
    int o00t = y0ti * WW + x0ti, o01t = y0ti * WW + x1ti;
    int o10t = y1ti * WW + x0ti, o11t = y1ti * WW + x1ti;

    const float* rp = rgb + (size_t)b * CCH * NPIX;
    const float* tp = tir + (size_t)b * CCH * NPIX;
    float* out_r = out + (size_t)b * CCH * NPIX;
    float* out_t = out + (size_t)BB * CCH * NPIX + (size_t)b * CCH * NPIX;
    const float* modb = mod + b * CCH;
    int pix = y * WW + x;

    float qacc = 0.f;
#pragma unroll 4
    for (int c = 0; c < CCH; c++) {
        const float* rpc = rp + (size_t)c * NPIX;
        float v00 = rpc[o00r], v01 = rpc[o01r], v10 = rpc[o10r], v11 = rpc[o11r];
        float topr = v00 + (v01 - v00) * wxr;
        float botr = v10 + (v11 - v10) * wxr;
        float sr = topr + (botr - topr) * wyr;

        const float* tpc = tp + (size_t)c * NPIX;
        float u00 = tpc[o00t], u01 = tpc[o01t], u10 = tpc[o10t], u11 = tpc[o11t];
        float topt = u00 + (u01 - u00) * wxt;
        float bott = u10 + (u11 - u10) * wxt;
        float st = topt + (bott - topt) * wyt;

        float mo = modb[c];
        float ra = sr * mo;
        float ta = st * mo;
        out_r[(size_t)c * NPIX + pix] = ra;
        out_t[(size_t)c * NPIX + pix] = ta;
        qacc += fabsf(ra - ta);
    }
    float q = 1.f - qacc * (1.f / (float)CCH);
    out[(size_t)2 * BB * CCH * NPIX + (size_t)b * NPIX + pix] = 1.f / (1.f + expf(-q));
}

extern "C" void kernel_launch(void* const* d_in, const int* in_sizes, int n_in,
                              void* d_out, int out_size, void* d_ws, size_t ws_size,
                              hipStream_t stream) {
    const float* rgb  = (const float*)d_in[0];
    const float* tir  = (const float*)d_in[1];
    const float* dw_w = (const float*)d_in[2];
    const float* dw_b = (const float*)d_in[3];
    const float* p1_w = (const float*)d_in[4];
    const float* p1_b = (const float*)d_in[5];
    const float* p2_w = (const float*)d_in[6];
    const float* p2_b = (const float*)d_in[7];
    const float* m1_w = (const float*)d_in[8];
    const float* m1_b = (const float*)d_in[9];
    const float* m2_w = (const float*)d_in[10];
    const float* m2_b = (const float*)d_in[11];
    float* out = (float*)d_out;
    float* ws  = (float*)d_ws;

    float* off4   = ws + OFF4_OFF;
    float* pooled = ws + POOLED_OFF;
    float* modw   = ws + MOD_OFF;
    float* w4     = ws + W4_OFF;
    float* b4     = ws + B4_OFF;
    unsigned short* p1bf = (unsigned short*)(ws + P1B_OFF);

    hipLaunchKernelGGL(k_prep, dim3(1), dim3(64), 0, stream, p2_w, p2_b, w4, b4);
    hipLaunchKernelGGL(k_prep_p1, dim3(128), dim3(256), 0, stream, p1_w, p1bf);
    hipLaunchKernelGGL(k_pool, dim3(BB * C2), dim3(256), 0, stream, rgb, tir, pooled);
    hipLaunchKernelGGL(k_mod, dim3(BB), dim3(64), 0, stream,
                       pooled, m1_w, m1_b, m2_w, m2_b, modw);
    hipLaunchKernelGGL(k_offsets, dim3(BB * (HH / 2)), dim3(256), 0, stream,
                       rgb, tir, dw_w, dw_b, p1_b, p1bf, w4, b4, off4);
    hipLaunchKernelGGL(k_sample, dim3(BB * NPIX / 256), dim3(256), 0, stream,
                       rgb, tir, off4, modw, out);
}